// Round 1
// baseline (286.646 us; speedup 1.0000x reference)
//
#include <hip/hip_runtime.h>

// Problem: B=16, C=3, H=256, W=256 fp32. 48 slices of 256x256.
// out = inverted, per-slice max-normalized, per-channel-weighted exact EDT.

#define BIGD 512.0f   // H + W, matches reference cap

// ---------------- K1: row pass (1D distance to nearest zero along W) --------
// One thread per row (B*C*H = 12288 rows). Writes g^2 (float) into d_out as temp.
__global__ void k1_rowpass(const float* __restrict__ in, float* __restrict__ g2out) {
    int t = blockIdx.x * blockDim.x + threadIdx.x;   // row id 0..12287
    const float4* in4 = (const float4*)in;
    float4* o4 = (float4*)g2out;
    long b = (long)t * 64;                           // 64 float4 per row

    // forward scan: d = m ? min(carry+1, BIG) : 0
    float carry = BIGD;
    #pragma unroll 8
    for (int i = 0; i < 64; ++i) {
        float4 m = in4[b + i];
        float4 d;
        d.x = (m.x != 0.f) ? fminf(carry + 1.f, BIGD) : 0.f; carry = d.x;
        d.y = (m.y != 0.f) ? fminf(carry + 1.f, BIGD) : 0.f; carry = d.y;
        d.z = (m.z != 0.f) ? fminf(carry + 1.f, BIGD) : 0.f; carry = d.z;
        d.w = (m.w != 0.f) ? fminf(carry + 1.f, BIGD) : 0.f; carry = d.w;
        o4[b + i] = d;
    }
    // backward scan, combine, square
    carry = BIGD;
    #pragma unroll 8
    for (int i = 63; i >= 0; --i) {
        float4 m = in4[b + i];
        float4 f = o4[b + i];
        float4 g;
        float d;
        d = (m.w != 0.f) ? fminf(carry + 1.f, BIGD) : 0.f; carry = d; g.w = fminf(f.w, d); g.w *= g.w;
        d = (m.z != 0.f) ? fminf(carry + 1.f, BIGD) : 0.f; carry = d; g.z = fminf(f.z, d); g.z *= g.z;
        d = (m.y != 0.f) ? fminf(carry + 1.f, BIGD) : 0.f; carry = d; g.y = fminf(f.y, d); g.y *= g.y;
        d = (m.x != 0.f) ? fminf(carry + 1.f, BIGD) : 0.f; carry = d; g.x = fminf(f.x, d); g.x *= g.x;
        o4[b + i] = g;
    }
}

// ---------------- K2: exact min-plus column pass + per-slice max ------------
// Block = 256 threads handles one slice's 64-column strip (grid 48*4 = 192).
// Loads g2 tile [256 rows][64 cols] into LDS, brute-forces min over all 256
// candidate rows, writes d2 back in place, atomicMax per-slice max (float bits).
__global__ __launch_bounds__(256) void k2_colpass(float* __restrict__ d2,
                                                  unsigned int* __restrict__ mxbits) {
    __shared__ float tile[256 * 64];   // 64 KB
    int bx = blockIdx.x;
    int slice = bx >> 2;
    int w0 = (bx & 3) * 64;
    int tid = threadIdx.x;
    float* src = d2 + (long)slice * 65536 + w0;

    // coalesced tile load (float4)
    float4* t4 = (float4*)tile;
    #pragma unroll
    for (int k = 0; k < 16; ++k) {
        int lin = k * 256 + tid;       // float4 index, 0..4095
        int r = lin >> 4;              // 16 float4 per 64-col row
        int q = lin & 15;
        t4[lin] = *((const float4*)(src + (long)r * 256) + q);
    }
    __syncthreads();

    int w  = tid & 63;                 // column within strip
    int r0 = (tid >> 6) * 64;          // this thread owns rows r0..r0+63

    float dmin[64];
    #pragma unroll
    for (int k = 0; k < 64; ++k) dmin[k] = 3.0e38f;

    for (int rp = 0; rp < 256; ++rp) {
        float g = tile[rp * 64 + w];   // 2-way bank alias only (free)
        float e = (float)(rp - r0);
        #pragma unroll
        for (int k = 0; k < 64; ++k) {
            float u = (float)k - e;    // = (r - rp), r = r0 + k
            dmin[k] = fminf(dmin[k], fmaf(u, u, g));
        }
    }

    // write back d2 in place, track max
    float m = 0.f;
    float* dst = d2 + (long)slice * 65536 + w0 + w;
    #pragma unroll
    for (int k = 0; k < 64; ++k) {
        dst[(long)(r0 + k) * 256] = dmin[k];
        m = fmaxf(m, dmin[k]);
    }
    // wave (64-lane) max reduce, one atomic per wave
    #pragma unroll
    for (int off = 32; off >= 1; off >>= 1)
        m = fmaxf(m, __shfl_down(m, off, 64));
    if ((tid & 63) == 0)
        atomicMax((int*)&mxbits[slice], __float_as_int(m));   // d2 >= 0 -> int order ok
}

// ---------------- K3: epilogue --------------------------------------------
// out = mx>0 ? (mx - dt)/mx : dt, dt = w_c * sqrt(d2), in place on d_out.
__global__ void k3_final(float* __restrict__ out, const unsigned int* __restrict__ mxbits) {
    int idx4 = blockIdx.x * blockDim.x + threadIdx.x;   // float4 index, 786432 total
    long base = (long)idx4 * 4;
    int slice = (int)(base >> 16);                      // 65536 elems per slice
    int c = slice % 3;
    float wgt = (c == 0) ? 0.5f : ((c == 1) ? 1.0f : 2.0f);
    float maxd2 = __int_as_float((int)mxbits[slice]);
    float mx = wgt * __builtin_sqrtf(maxd2);

    float4 d2 = ((float4*)out)[idx4];
    float4 r;
    if (mx > 0.f) {
        float inv = 1.0f / mx;
        r.x = (mx - wgt * __builtin_sqrtf(d2.x)) * inv;
        r.y = (mx - wgt * __builtin_sqrtf(d2.y)) * inv;
        r.z = (mx - wgt * __builtin_sqrtf(d2.z)) * inv;
        r.w = (mx - wgt * __builtin_sqrtf(d2.w)) * inv;
    } else {
        r.x = wgt * __builtin_sqrtf(d2.x);
        r.y = wgt * __builtin_sqrtf(d2.y);
        r.z = wgt * __builtin_sqrtf(d2.z);
        r.w = wgt * __builtin_sqrtf(d2.w);
    }
    ((float4*)out)[idx4] = r;
}

extern "C" void kernel_launch(void* const* d_in, const int* in_sizes, int n_in,
                              void* d_out, int out_size, void* d_ws, size_t ws_size,
                              hipStream_t stream) {
    const float* in = (const float*)d_in[0];
    float* out = (float*)d_out;
    unsigned int* mx = (unsigned int*)d_ws;

    // per-slice max accumulators (48 floats) — ws is poisoned, zero them
    hipMemsetAsync(d_ws, 0, 48 * sizeof(unsigned int), stream);

    k1_rowpass<<<48, 256, 0, stream>>>(in, out);       // 12288 rows
    k2_colpass<<<192, 256, 0, stream>>>(out, mx);      // 48 slices x 4 strips
    k3_final<<<3072, 256, 0, stream>>>(out, mx);       // 786432 float4
}

// Round 2
// 106.210 us; speedup vs baseline: 2.6989x; 2.6989x over previous
//
#include <hip/hip_runtime.h>

// B=16, C=3, H=256, W=256 fp32. 48 slices of 256x256.
// out = inverted, per-slice max-normalized, per-channel-weighted exact EDT.
//
// Pipeline:
//   K1: ballot-based row pass (wave per row) -> g^2 into d_out
//   K2: windowed (+-16) exact min-plus column pass, in-place, + per-slice max
//       + exactness certificate (windowed result <= 288 => provably exact)
//   K2fix: full exact recompute fallback, early-exits unless certificate failed
//   K3: epilogue  out = (mx - w*sqrt(d2))/mx  (inverted, safe at mx==0)

#define BIGD 512.0f

// ---------------- K1: row pass via ballots ---------------------------------
// One wave per row. Lane l holds elements 4l..4l+3. Four 64-bit zero-masks
// (one per component class); nearest zero = clz/ctz search over the masks.
__global__ __launch_bounds__(256) void k1_rowpass(const float* __restrict__ in,
                                                  float* __restrict__ g2out) {
    int row = blockIdx.x * 4 + (threadIdx.x >> 6);
    int lane = threadIdx.x & 63;
    const float4 m = ((const float4*)in)[(long)row * 64 + lane];

    unsigned long long bz[4];
    bz[0] = __ballot(m.x == 0.f);
    bz[1] = __ballot(m.y == 0.f);
    bz[2] = __ballot(m.z == 0.f);
    bz[3] = __ballot(m.w == 0.f);

    auto nz2 = [&](int p) -> float {   // squared capped distance to nearest zero
        int dist = 512;                 // BIG cap (H+W), matches reference
        #pragma unroll
        for (int cc = 0; cc < 4; ++cc) {
            unsigned long long M = bz[cc];
            int q = p - cc;                          // >= -3
            int qa = (q < 0) ? 0 : q;
            int tp = qa >> 2;                        // floor(q/4), valid for q>=0
            unsigned long long Ml = (q >= 0) ? (M & (~0ull >> (63 - tp))) : 0ull;
            int tn = (q < 0) ? 0 : ((q + 3) >> 2);   // ceil(q/4)
            unsigned long long Mh = (tn < 64) ? (M & (~0ull << tn)) : 0ull;
            if (Ml) dist = min(dist, q - 4 * (63 - __builtin_clzll(Ml)));
            if (Mh) dist = min(dist, 4 * __builtin_ctzll(Mh) - q);
        }
        float fd = (float)dist;
        return fd * fd;
    };

    int p0 = 4 * lane;
    float4 g;
    g.x = nz2(p0 + 0);
    g.y = nz2(p0 + 1);
    g.z = nz2(p0 + 2);
    g.w = nz2(p0 + 3);
    ((float4*)g2out)[(long)row * 64 + lane] = g;
}

// ---------------- K2: windowed exact min-plus column pass ------------------
// Block = 256 threads = one slice's 16-col strip. Tile is column-major with
// stride 289 (odd -> conflict-free LDS reads) and 16 pad rows of +inf on each
// side. Thread owns 16 rows of 1 column: stage 48 floats to registers, fully
// unrolled 33-offset window. Certificate: windowed min <= 288 => exact
// (any |o|>=17 candidate >= 289).
#define PADV 1e30f
__global__ __launch_bounds__(256) void k2_colpass(const float* __restrict__ g2,
                                                  float* __restrict__ d2out,
                                                  unsigned int* __restrict__ mxbits,
                                                  unsigned int* __restrict__ flag) {
    __shared__ float tile[16 * 289];
    int bx = blockIdx.x;
    int slice = bx >> 4;
    int w0 = (bx & 15) * 16;
    int tid = threadIdx.x;
    const float* src = g2 + (long)slice * 65536 + w0;

    // pad rows (entries 0..15 and 272..287 of each column)
    {
        int c = tid >> 4, i = tid & 15;
        tile[c * 289 + i] = PADV;
        tile[c * 289 + 272 + i] = PADV;
    }
    // tile load: 1024 float4 = 4 per thread; LDS write is 2-way bank alias (free)
    #pragma unroll
    for (int it = 0; it < 4; ++it) {
        int f = it * 256 + tid;
        int row = f >> 2;
        int quad = f & 3;
        float4 v = *((const float4*)(src + (long)row * 256) + quad);
        int cb = quad * 4;
        tile[(cb + 0) * 289 + 16 + row] = v.x;
        tile[(cb + 1) * 289 + 16 + row] = v.y;
        tile[(cb + 2) * 289 + 16 + row] = v.z;
        tile[(cb + 3) * 289 + 16 + row] = v.w;
    }
    __syncthreads();

    int c = tid & 15;
    int r0 = (tid >> 4) * 16;          // owned rows r0..r0+15

    float s[48];                        // rows r0-16 .. r0+31 of column c
    #pragma unroll
    for (int i = 0; i < 48; ++i) s[i] = tile[c * 289 + r0 + i];

    float dmin[16];
    #pragma unroll
    for (int k = 0; k < 16; ++k) dmin[k] = s[k + 16];   // o = 0
    #pragma unroll
    for (int o = -16; o <= 16; ++o) {
        if (o == 0) continue;
        float oo = (float)(o * o);
        #pragma unroll
        for (int k = 0; k < 16; ++k)
            dmin[k] = fminf(dmin[k], s[k + 16 + o] + oo);
    }

    float* dst = d2out + (long)slice * 65536 + w0 + c;
    float m = 0.f;
    #pragma unroll
    for (int k = 0; k < 16; ++k) {
        dst[(long)(r0 + k) * 256] = dmin[k];
        m = fmaxf(m, dmin[k]);
    }
    if (m > 288.0f) atomicOr(flag, 1u);      // can't certify -> fallback will run

    #pragma unroll
    for (int off = 32; off >= 1; off >>= 1)
        m = fmaxf(m, __shfl_down(m, off, 64));
    if ((tid & 63) == 0)
        atomicMax((int*)&mxbits[slice], __float_as_int(m));  // d2 >= 0: int order ok
}

// ---------------- K2fix: exact fallback (normally a no-op) -----------------
// One block per slice. Recomputes g2 from the input mask and does the full
// 256-candidate min-plus. Only correctness matters; it never runs in practice.
__global__ __launch_bounds__(256) void k2_fix(const float* __restrict__ in,
                                              float* __restrict__ d2,
                                              unsigned int* __restrict__ mxbits,
                                              const unsigned int* __restrict__ flag) {
    if (*flag == 0) return;
    int slice = blockIdx.x;
    int t = threadIdx.x;

    // phase A: row scan (thread t = row t) -> g2 overwrites d2[slice]
    {
        const float* rin = in + (long)slice * 65536 + (long)t * 256;
        float* rout = d2 + (long)slice * 65536 + (long)t * 256;
        float f[256];
        float carry = BIGD;
        for (int i = 0; i < 256; ++i) {
            carry = (rin[i] != 0.f) ? fminf(carry + 1.f, BIGD) : 0.f;
            f[i] = carry;
        }
        carry = BIGD;
        for (int i = 255; i >= 0; --i) {
            carry = (rin[i] != 0.f) ? fminf(carry + 1.f, BIGD) : 0.f;
            float g = fminf(f[i], carry);
            rout[i] = g * g;
        }
    }
    __threadfence();
    __syncthreads();

    // phase B: thread t = column t, full min-plus in registers/scratch
    float col[256];
    float* base = d2 + (long)slice * 65536 + t;
    for (int r = 0; r < 256; ++r) col[r] = base[(long)r * 256];
    float mx = 0.f;
    for (int r = 0; r < 256; ++r) {
        float best = 3e38f;
        for (int rp = 0; rp < 256; ++rp) {
            float dr = (float)(r - rp);
            best = fminf(best, fmaf(dr, dr, col[rp]));
        }
        base[(long)r * 256] = best;
        mx = fmaxf(mx, best);
    }
    __shared__ float red[4];
    #pragma unroll
    for (int off = 32; off >= 1; off >>= 1) mx = fmaxf(mx, __shfl_down(mx, off, 64));
    if ((t & 63) == 0) red[t >> 6] = mx;
    __syncthreads();
    if (t == 0) {
        float m = fmaxf(fmaxf(red[0], red[1]), fmaxf(red[2], red[3]));
        mxbits[slice] = (unsigned int)__float_as_int(m);   // plain store: overrides K2's
    }
}

// ---------------- K3: epilogue ---------------------------------------------
__global__ void k3_final(float* __restrict__ out, const unsigned int* __restrict__ mxbits) {
    int idx4 = blockIdx.x * blockDim.x + threadIdx.x;   // 786432 float4
    long base = (long)idx4 * 4;
    int slice = (int)(base >> 16);
    int c = slice % 3;
    float wgt = (c == 0) ? 0.5f : ((c == 1) ? 1.0f : 2.0f);
    float maxd2 = __int_as_float((int)mxbits[slice]);
    float mx = wgt * __builtin_sqrtf(maxd2);

    float4 d2 = ((float4*)out)[idx4];
    float4 r;
    if (mx > 0.f) {
        float inv = 1.0f / mx;
        r.x = (mx - wgt * __builtin_sqrtf(d2.x)) * inv;
        r.y = (mx - wgt * __builtin_sqrtf(d2.y)) * inv;
        r.z = (mx - wgt * __builtin_sqrtf(d2.z)) * inv;
        r.w = (mx - wgt * __builtin_sqrtf(d2.w)) * inv;
    } else {
        r.x = wgt * __builtin_sqrtf(d2.x);
        r.y = wgt * __builtin_sqrtf(d2.y);
        r.z = wgt * __builtin_sqrtf(d2.z);
        r.w = wgt * __builtin_sqrtf(d2.w);
    }
    ((float4*)out)[idx4] = r;
}

extern "C" void kernel_launch(void* const* d_in, const int* in_sizes, int n_in,
                              void* d_out, int out_size, void* d_ws, size_t ws_size,
                              hipStream_t stream) {
    const float* in = (const float*)d_in[0];
    float* out = (float*)d_out;
    unsigned int* mx = (unsigned int*)d_ws;       // [0..47] per-slice max bits
    unsigned int* flag = mx + 48;                 // [48] certificate-failure flag

    hipMemsetAsync(d_ws, 0, 256, stream);

    k1_rowpass<<<3072, 256, 0, stream>>>(in, out);        // 12288 rows, wave/row
    k2_colpass<<<768, 256, 0, stream>>>(out, out, mx, flag);  // in-place per strip
    k2_fix<<<48, 256, 0, stream>>>(in, out, mx, flag);    // no-op unless flagged
    k3_final<<<3072, 256, 0, stream>>>(out, mx);          // 786432 float4
}

// Round 3
// 87.494 us; speedup vs baseline: 3.2762x; 1.2139x over previous
//
#include <hip/hip_runtime.h>

// B=16, C=3, H=256, W=256 fp32. 48 slices of 256x256.
// out = inverted, per-slice max-normalized, per-channel-weighted exact EDT.
//
// Pipeline (no memset, no atomics — every d_ws slot used is written each call):
//   K1: ballot-based row pass (wave per row) -> g^2 into d_out
//   K2: windowed (+-16) exact min-plus column pass, in-place; plain-store
//       per-strip max into ws[bx] (doubles as exactness certificate: >288
//       means the +-16 window may be inexact for some pixel in the strip)
//   K2fix: per-slice full exact recompute; early-exits unless its slice's
//       strip maxes show a certificate failure (never in practice)
//   K3: epilogue out = (mx - w*sqrt(d2))/mx; slice max = max of 16 strip maxes

#define BIGD 512.0f

// ---------------- K1: row pass via ballots ---------------------------------
// One wave per row. Lane l holds elements 4l..4l+3. Four 64-bit zero-masks
// (one per component class); nearest zero = clz/ctz search over the masks.
__global__ __launch_bounds__(256) void k1_rowpass(const float* __restrict__ in,
                                                  float* __restrict__ g2out) {
    int row = blockIdx.x * 4 + (threadIdx.x >> 6);
    int lane = threadIdx.x & 63;
    const float4 m = ((const float4*)in)[(long)row * 64 + lane];

    unsigned long long bz[4];
    bz[0] = __ballot(m.x == 0.f);
    bz[1] = __ballot(m.y == 0.f);
    bz[2] = __ballot(m.z == 0.f);
    bz[3] = __ballot(m.w == 0.f);

    auto nz2 = [&](int p) -> float {   // squared capped distance to nearest zero
        int dist = 512;                 // BIG cap (H+W), matches reference
        #pragma unroll
        for (int cc = 0; cc < 4; ++cc) {
            unsigned long long M = bz[cc];
            int q = p - cc;                          // >= -3
            int qa = (q < 0) ? 0 : q;
            int tp = qa >> 2;                        // floor(q/4), valid for q>=0
            unsigned long long Ml = (q >= 0) ? (M & (~0ull >> (63 - tp))) : 0ull;
            int tn = (q < 0) ? 0 : ((q + 3) >> 2);   // ceil(q/4)
            unsigned long long Mh = (tn < 64) ? (M & (~0ull << tn)) : 0ull;
            if (Ml) dist = min(dist, q - 4 * (63 - __builtin_clzll(Ml)));
            if (Mh) dist = min(dist, 4 * __builtin_ctzll(Mh) - q);
        }
        float fd = (float)dist;
        return fd * fd;
    };

    int p0 = 4 * lane;
    float4 g;
    g.x = nz2(p0 + 0);
    g.y = nz2(p0 + 1);
    g.z = nz2(p0 + 2);
    g.w = nz2(p0 + 3);
    ((float4*)g2out)[(long)row * 64 + lane] = g;
}

// ---------------- K2: windowed exact min-plus column pass ------------------
// Block = 256 threads = one slice's 16-col strip. Tile is column-major with
// stride 289 (odd -> conflict-free LDS reads) and 16 pad rows of +inf on each
// side. Thread owns 16 rows of 1 column: stage 48 floats to registers, fully
// unrolled 33-offset window. stripmax[bx] is ALWAYS written (plain store).
#define PADV 1e30f
__global__ __launch_bounds__(256) void k2_colpass(const float* __restrict__ g2,
                                                  float* __restrict__ d2out,
                                                  float* __restrict__ stripmax) {
    __shared__ float tile[16 * 289];
    __shared__ float wm[4];
    int bx = blockIdx.x;
    int slice = bx >> 4;
    int w0 = (bx & 15) * 16;
    int tid = threadIdx.x;
    const float* src = g2 + (long)slice * 65536 + w0;

    // pad rows (entries 0..15 and 272..287 of each column)
    {
        int c = tid >> 4, i = tid & 15;
        tile[c * 289 + i] = PADV;
        tile[c * 289 + 272 + i] = PADV;
    }
    // tile load: 1024 float4 = 4 per thread; LDS write is 2-way bank alias (free)
    #pragma unroll
    for (int it = 0; it < 4; ++it) {
        int f = it * 256 + tid;
        int row = f >> 2;
        int quad = f & 3;
        float4 v = *((const float4*)(src + (long)row * 256) + quad);
        int cb = quad * 4;
        tile[(cb + 0) * 289 + 16 + row] = v.x;
        tile[(cb + 1) * 289 + 16 + row] = v.y;
        tile[(cb + 2) * 289 + 16 + row] = v.z;
        tile[(cb + 3) * 289 + 16 + row] = v.w;
    }
    __syncthreads();

    int c = tid & 15;
    int r0 = (tid >> 4) * 16;          // owned rows r0..r0+15

    float s[48];                        // rows r0-16 .. r0+31 of column c
    #pragma unroll
    for (int i = 0; i < 48; ++i) s[i] = tile[c * 289 + r0 + i];

    float dmin[16];
    #pragma unroll
    for (int k = 0; k < 16; ++k) dmin[k] = s[k + 16];   // o = 0
    #pragma unroll
    for (int o = -16; o <= 16; ++o) {
        if (o == 0) continue;
        float oo = (float)(o * o);
        #pragma unroll
        for (int k = 0; k < 16; ++k)
            dmin[k] = fminf(dmin[k], s[k + 16 + o] + oo);
    }

    float* dst = d2out + (long)slice * 65536 + w0 + c;
    float m = 0.f;
    #pragma unroll
    for (int k = 0; k < 16; ++k) {
        dst[(long)(r0 + k) * 256] = dmin[k];
        m = fmaxf(m, dmin[k]);
    }

    // block max (4 waves) -> plain store, no init required
    #pragma unroll
    for (int off = 32; off >= 1; off >>= 1)
        m = fmaxf(m, __shfl_down(m, off, 64));
    if ((tid & 63) == 0) wm[tid >> 6] = m;
    __syncthreads();
    if (tid == 0)
        stripmax[bx] = fmaxf(fmaxf(wm[0], wm[1]), fmaxf(wm[2], wm[3]));
}

// ---------------- K2fix: exact fallback (normally a no-op) -----------------
// One block per slice. Triggered iff any of the slice's 16 strip maxes > 288
// (i.e. the +-16 window could not be certified exact). Recomputes g2 from the
// input mask, does the full 256-candidate min-plus, and overwrites the strip
// maxes with the true slice max so K3 sees consistent data.
__global__ __launch_bounds__(256) void k2_fix(const float* __restrict__ in,
                                              float* __restrict__ d2,
                                              float* __restrict__ stripmax) {
    int slice = blockIdx.x;
    int t = threadIdx.x;
    __shared__ float sm;
    if (t < 16) {
        float v = stripmax[slice * 16 + t];
        #pragma unroll
        for (int off = 8; off >= 1; off >>= 1) v = fmaxf(v, __shfl_down(v, off, 64));
        if (t == 0) sm = v;
    }
    __syncthreads();
    if (sm <= 288.0f) return;          // certified exact -> nothing to do

    // phase A: row scan (thread t = row t) -> g2 overwrites d2[slice]
    {
        const float* rin = in + (long)slice * 65536 + (long)t * 256;
        float* rout = d2 + (long)slice * 65536 + (long)t * 256;
        float f[256];
        float carry = BIGD;
        for (int i = 0; i < 256; ++i) {
            carry = (rin[i] != 0.f) ? fminf(carry + 1.f, BIGD) : 0.f;
            f[i] = carry;
        }
        carry = BIGD;
        for (int i = 255; i >= 0; --i) {
            carry = (rin[i] != 0.f) ? fminf(carry + 1.f, BIGD) : 0.f;
            float g = fminf(f[i], carry);
            rout[i] = g * g;
        }
    }
    __threadfence();
    __syncthreads();

    // phase B: thread t = column t, full min-plus
    float col[256];
    float* base = d2 + (long)slice * 65536 + t;
    for (int r = 0; r < 256; ++r) col[r] = base[(long)r * 256];
    float mx = 0.f;
    for (int r = 0; r < 256; ++r) {
        float best = 3e38f;
        for (int rp = 0; rp < 256; ++rp) {
            float dr = (float)(r - rp);
            best = fminf(best, fmaf(dr, dr, col[rp]));
        }
        base[(long)r * 256] = best;
        mx = fmaxf(mx, best);
    }
    __shared__ float red[4];
    #pragma unroll
    for (int off = 32; off >= 1; off >>= 1) mx = fmaxf(mx, __shfl_down(mx, off, 64));
    if ((t & 63) == 0) red[t >> 6] = mx;
    __syncthreads();
    if (t == 0) {
        float m = fmaxf(fmaxf(red[0], red[1]), fmaxf(red[2], red[3]));
        #pragma unroll
        for (int i = 0; i < 16; ++i) stripmax[slice * 16 + i] = m;
    }
}

// ---------------- K3: epilogue ---------------------------------------------
// 64 blocks per slice; each block reduces the slice's 16 strip maxes once.
__global__ __launch_bounds__(256) void k3_final(float* __restrict__ out,
                                                const float* __restrict__ stripmax) {
    __shared__ float sMx;
    int tid = threadIdx.x;
    int idx4 = blockIdx.x * 256 + tid;    // float4 index, 786432 total
    int slice = blockIdx.x >> 6;          // 16384 float4 per slice / 256 = 64 blocks
    if (tid < 16) {
        float v = stripmax[slice * 16 + tid];
        #pragma unroll
        for (int off = 8; off >= 1; off >>= 1) v = fmaxf(v, __shfl_down(v, off, 64));
        if (tid == 0) sMx = v;
    }
    __syncthreads();

    int c = slice % 3;
    float wgt = (c == 0) ? 0.5f : ((c == 1) ? 1.0f : 2.0f);
    float mx = wgt * __builtin_sqrtf(sMx);

    float4 d2 = ((float4*)out)[idx4];
    float4 r;
    if (mx > 0.f) {
        float inv = 1.0f / mx;
        r.x = (mx - wgt * __builtin_sqrtf(d2.x)) * inv;
        r.y = (mx - wgt * __builtin_sqrtf(d2.y)) * inv;
        r.z = (mx - wgt * __builtin_sqrtf(d2.z)) * inv;
        r.w = (mx - wgt * __builtin_sqrtf(d2.w)) * inv;
    } else {
        r.x = wgt * __builtin_sqrtf(d2.x);
        r.y = wgt * __builtin_sqrtf(d2.y);
        r.z = wgt * __builtin_sqrtf(d2.z);
        r.w = wgt * __builtin_sqrtf(d2.w);
    }
    ((float4*)out)[idx4] = r;
}

extern "C" void kernel_launch(void* const* d_in, const int* in_sizes, int n_in,
                              void* d_out, int out_size, void* d_ws, size_t ws_size,
                              hipStream_t stream) {
    const float* in = (const float*)d_in[0];
    float* out = (float*)d_out;
    float* stripmax = (float*)d_ws;               // [0..767], one per 16-col strip

    k1_rowpass<<<3072, 256, 0, stream>>>(in, out);        // 12288 rows, wave/row
    k2_colpass<<<768, 256, 0, stream>>>(out, out, stripmax);
    k2_fix<<<48, 256, 0, stream>>>(in, out, stripmax);    // no-op unless uncertified
    k3_final<<<3072, 256, 0, stream>>>(out, stripmax);    // 786432 float4
}

// Round 4
// 83.013 us; speedup vs baseline: 3.4530x; 1.0540x over previous
//
#include <hip/hip_runtime.h>

// B=16, C=3, H=256, W=256 fp32. 48 slices of 256x256.
// out = inverted, per-slice max-normalized, per-channel-weighted exact EDT.
//
// Pipeline (3 launches, no atomics, no fallback kernel):
//   K1: wave per row -> four 64-bit zero-ballots per row (bitmask, 32 B/row)
//       into d_ws. 12.6 MB read, 0.4 MB written (vs 12.6 MB g2 before).
//   K2: per 16-col strip: slice bitmask (8 KB) -> LDS; compute g^2 in-LDS via
//       clz/ctz nearest-zero search; +-16 windowed min-plus; per-pixel EXACT
//       fallback (full 256-row column scan in LDS) whenever windowed min > 288
//       (|o|>=17 candidates are >= 289, so <=288 certifies exactness).
//       Writes d2 -> d_out, per-strip max -> d_ws (plain store, always).
//   K3: epilogue out = (mx - w*sqrt(d2))/mx; slice max = max of 16 strip maxes.

#define BIGD 512.0f
#define PADV 1e30f

// ---------------- K1: row bitmask via ballots -------------------------------
// One wave per row. Lane l holds cols 4l..4l+3; bz[cc] bit l = (col 4l+cc == 0).
__global__ __launch_bounds__(256) void k1_bitmask(const float* __restrict__ in,
                                                  unsigned long long* __restrict__ bits) {
    int row = blockIdx.x * 4 + (threadIdx.x >> 6);
    int lane = threadIdx.x & 63;
    const float4 m = ((const float4*)in)[(long)row * 64 + lane];

    unsigned long long b0 = __ballot(m.x == 0.f);
    unsigned long long b1 = __ballot(m.y == 0.f);
    unsigned long long b2 = __ballot(m.z == 0.f);
    unsigned long long b3 = __ballot(m.w == 0.f);
    if (lane == 0) {
        ulonglong4* dst = (ulonglong4*)(bits + (long)row * 4);
        ulonglong4 v; v.x = b0; v.y = b1; v.z = b2; v.w = b3;
        *dst = v;
    }
}

// ---------------- K2: g2 from bitmask + exact min-plus column pass ----------
// Block = 256 threads = one slice's 16-col strip (grid 48*16).
// LDS: slice bitmask (256 rows x 4 ull = 8 KB) + column-major g2 tile with
// stride 289 (odd -> benign banking) and 16 pad rows each side.
__global__ __launch_bounds__(256) void k2_colpass(const unsigned long long* __restrict__ bits,
                                                  float* __restrict__ d2out,
                                                  float* __restrict__ stripmax) {
    __shared__ unsigned long long bm[1024];   // [row*4 + cc]
    __shared__ float tile[16 * 289];
    __shared__ float wm[4];
    int bx = blockIdx.x;
    int slice = bx >> 4;
    int w0 = (bx & 15) * 16;
    int tid = threadIdx.x;

    // load slice bitmask: 1024 ull, coalesced
    {
        const unsigned long long* src = bits + (long)slice * 1024;
        #pragma unroll
        for (int i = 0; i < 4; ++i) bm[i * 256 + tid] = src[i * 256 + tid];
    }
    // pad rows of the tile
    {
        int c = tid >> 4, i = tid & 15;
        tile[c * 289 + i] = PADV;
        tile[c * 289 + 272 + i] = PADV;
    }
    __syncthreads();

    int c = tid & 15;                 // column within strip
    int p = w0 + c;                   // global column 0..255
    int rg = tid >> 4;                // 0..15

    // nearest-zero squared distance for (row, col p) from LDS bitmask
    auto nz2 = [&](int row) -> float {
        int dist = 512;               // BIG cap (H+W), matches reference
        #pragma unroll
        for (int cc = 0; cc < 4; ++cc) {
            unsigned long long M = bm[row * 4 + cc];
            int q = p - cc;                          // >= -3
            int qa = (q < 0) ? 0 : q;
            int tp = qa >> 2;                        // floor(q/4) for q>=0
            unsigned long long Ml = (q >= 0) ? (M & (~0ull >> (63 - tp))) : 0ull;
            int tn = (q < 0) ? 0 : ((q + 3) >> 2);   // ceil(q/4)
            unsigned long long Mh = (tn < 64) ? (M & (~0ull << tn)) : 0ull;
            if (Ml) dist = min(dist, q - 4 * (63 - __builtin_clzll(Ml)));
            if (Mh) dist = min(dist, 4 * __builtin_ctzll(Mh) - q);
        }
        float fd = (float)dist;
        return fd * fd;
    };

    // compute g2 for 16 rows (strided assignment: rows rg, rg+16, ... -> <=2-way
    // bank alias on tile writes; bm reads are wave-broadcast per rgroup)
    #pragma unroll
    for (int k = 0; k < 16; ++k) {
        int r = rg + 16 * k;
        tile[c * 289 + 16 + r] = nz2(r);
    }
    __syncthreads();

    // window pass: contiguous ownership rows r0..r0+15
    int r0 = rg * 16;
    float s[48];                       // rows r0-16 .. r0+31 of column c
    #pragma unroll
    for (int i = 0; i < 48; ++i) s[i] = tile[c * 289 + r0 + i];

    float dmin[16];
    #pragma unroll
    for (int k = 0; k < 16; ++k) dmin[k] = s[k + 16];   // o = 0
    #pragma unroll
    for (int o = -16; o <= 16; ++o) {
        if (o == 0) continue;
        float oo = (float)(o * o);
        #pragma unroll
        for (int k = 0; k < 16; ++k)
            dmin[k] = fminf(dmin[k], s[k + 16 + o] + oo);
    }

    // per-pixel exact fallback: windowed min > 288 can't certify optimality
    // within +-16; rescan the full column (already in LDS). Never taken for
    // random masks -> execz-skipped; exactness is unconditional.
    #pragma unroll
    for (int k = 0; k < 16; ++k) {
        if (dmin[k] > 288.0f) {
            float best = dmin[k];
            int r = r0 + k;
            for (int rp = 0; rp < 256; ++rp) {
                float dr = (float)(r - rp);
                best = fminf(best, fmaf(dr, dr, tile[c * 289 + 16 + rp]));
            }
            dmin[k] = best;
        }
    }

    // write back d2, track block max
    float* dst = d2out + (long)slice * 65536 + w0 + c;
    float m = 0.f;
    #pragma unroll
    for (int k = 0; k < 16; ++k) {
        dst[(long)(r0 + k) * 256] = dmin[k];
        m = fmaxf(m, dmin[k]);
    }
    #pragma unroll
    for (int off = 32; off >= 1; off >>= 1)
        m = fmaxf(m, __shfl_down(m, off, 64));
    if ((tid & 63) == 0) wm[tid >> 6] = m;
    __syncthreads();
    if (tid == 0)
        stripmax[bx] = fmaxf(fmaxf(wm[0], wm[1]), fmaxf(wm[2], wm[3]));
}

// ---------------- K3: epilogue ---------------------------------------------
// 64 blocks per slice; each block reduces the slice's 16 strip maxes once.
__global__ __launch_bounds__(256) void k3_final(float* __restrict__ out,
                                                const float* __restrict__ stripmax) {
    __shared__ float sMx;
    int tid = threadIdx.x;
    int idx4 = blockIdx.x * 256 + tid;    // float4 index, 786432 total
    int slice = blockIdx.x >> 6;          // 64 blocks per slice
    if (tid < 16) {
        float v = stripmax[slice * 16 + tid];
        #pragma unroll
        for (int off = 8; off >= 1; off >>= 1) v = fmaxf(v, __shfl_down(v, off, 64));
        if (tid == 0) sMx = v;
    }
    __syncthreads();

    int c = slice % 3;
    float wgt = (c == 0) ? 0.5f : ((c == 1) ? 1.0f : 2.0f);
    float mx = wgt * __builtin_sqrtf(sMx);

    float4 d2 = ((float4*)out)[idx4];
    float4 r;
    if (mx > 0.f) {
        float inv = 1.0f / mx;
        r.x = (mx - wgt * __builtin_sqrtf(d2.x)) * inv;
        r.y = (mx - wgt * __builtin_sqrtf(d2.y)) * inv;
        r.z = (mx - wgt * __builtin_sqrtf(d2.z)) * inv;
        r.w = (mx - wgt * __builtin_sqrtf(d2.w)) * inv;
    } else {
        r.x = wgt * __builtin_sqrtf(d2.x);
        r.y = wgt * __builtin_sqrtf(d2.y);
        r.z = wgt * __builtin_sqrtf(d2.z);
        r.w = wgt * __builtin_sqrtf(d2.w);
    }
    ((float4*)out)[idx4] = r;
}

extern "C" void kernel_launch(void* const* d_in, const int* in_sizes, int n_in,
                              void* d_out, int out_size, void* d_ws, size_t ws_size,
                              hipStream_t stream) {
    const float* in = (const float*)d_in[0];
    float* out = (float*)d_out;
    float* stripmax = (float*)d_ws;                                   // 768 floats
    unsigned long long* bits = (unsigned long long*)((char*)d_ws + 4096);  // 384 KB

    k1_bitmask<<<3072, 256, 0, stream>>>(in, bits);       // 12288 rows, wave/row
    k2_colpass<<<768, 256, 0, stream>>>(bits, out, stripmax);
    k3_final<<<3072, 256, 0, stream>>>(out, stripmax);    // 786432 float4
}